// Round 1
// baseline (749.848 us; speedup 1.0000x reference)
//
#include <hip/hip_runtime.h>

#define B_ 8
#define EH_ 768
#define T_ 512
#define PH_ 320
#define U_ 128
#define JH_ 320
#define C_ 34
#define TT 4          // t-rows per joint block
#define LDP 328       // padded LDS row stride (ushorts), keeps 16B alignment, breaks bank aliasing

typedef __bf16 bf16x8 __attribute__((ext_vector_type(8)));
typedef float f32x4 __attribute__((ext_vector_type(4)));

static __device__ __forceinline__ ushort f2bf(float f) {
    union { float f; unsigned u; } cv; cv.f = f;
    unsigned u = cv.u;
    unsigned r = (u + 0x7fffu + ((u >> 16) & 1u)) >> 16;   // RNE
    return (ushort)r;
}

// dst[b,n,j] = bias[j] + sum_h src[b,h,n] * W[j,h]   (stored as bf16)
// grid: (B, JH/16, N/128), block: 128
__global__ void proj_kernel(const float* __restrict__ src, const float* __restrict__ W,
                            const float* __restrict__ bias, ushort* __restrict__ dst,
                            int H, int N)
{
    const int b  = blockIdx.x;
    const int j0 = blockIdx.y * 16;
    const int n  = blockIdx.z * 128 + threadIdx.x;

    float acc[16];
#pragma unroll
    for (int jj = 0; jj < 16; ++jj) acc[jj] = bias[j0 + jj];

    const float* s = src + (size_t)b * H * N + n;
    for (int h = 0; h < H; ++h) {
        float v = s[(size_t)h * N];           // coalesced across threads (n fastest)
#pragma unroll
        for (int jj = 0; jj < 16; ++jj)       // W index is wave-uniform -> scalar loads
            acc[jj] = fmaf(v, W[(j0 + jj) * H + h], acc[jj]);
    }

    ushort* d = dst + ((size_t)b * N + n) * JH_ + j0;
#pragma unroll
    for (int jj = 0; jj < 16; jj += 2) {
        unsigned packed = (unsigned)f2bf(acc[jj]) | ((unsigned)f2bf(acc[jj + 1]) << 16);
        *(unsigned*)&d[jj] = packed;
    }
}

// Fused joint: logits = relu(e[t]+p[u]) @ W_out^T + b_out, then log_softmax over C=34.
// grid: (T/TT, 2, B), block: 256 (4 waves). Block tile: TT t's x 64 u's x 48 c (pad of 34).
__global__ __launch_bounds__(256) void joint_kernel(
    const ushort* __restrict__ e_bf, const ushort* __restrict__ p_bf,
    const float* __restrict__ W_out, const float* __restrict__ b_out,
    float* __restrict__ out)
{
    __shared__ alignas(16) ushort p_lds[64 * LDP];
    __shared__ alignas(16) ushort w_lds[48 * LDP];
    __shared__ alignas(16) ushort e_lds[TT * LDP];

    const int tid = threadIdx.x;
    const int t0  = blockIdx.x * TT;
    const int u0  = blockIdx.y * 64;
    const int b   = blockIdx.z;

    // ---- stage p rows u0..u0+63 (bf16, contiguous 2560 uint4) ----
    {
        const uint4* src = (const uint4*)(p_bf + ((size_t)b * U_ + u0) * JH_);
        for (int i = tid; i < 64 * 40; i += 256) {
            int r = i / 40, k8 = i % 40;
            uint4 v = src[i];
            *(uint4*)&p_lds[r * LDP + k8 * 8] = v;
        }
    }
    // ---- stage W_out 48x320 (c>=34 zero), fp32 -> bf16 ----
    {
        for (int i = tid; i < 48 * 80; i += 256) {
            int c = i / 80, k4 = i % 80;
            float4 w = (c < C_) ? ((const float4*)W_out)[c * 80 + k4] : make_float4(0.f, 0.f, 0.f, 0.f);
            ushort4 wb;
            wb.x = f2bf(w.x); wb.y = f2bf(w.y); wb.z = f2bf(w.z); wb.w = f2bf(w.w);
            *(ushort4*)&w_lds[c * LDP + k4 * 4] = wb;
        }
    }
    // ---- stage e rows t0..t0+TT-1 ----
    {
        const uint4* src = (const uint4*)(e_bf + ((size_t)b * T_ + t0) * JH_);
        for (int i = tid; i < TT * 40; i += 256) {
            int r = i / 40, k8 = i % 40;
            *(uint4*)&e_lds[r * LDP + k8 * 8] = src[i];
        }
    }
    __syncthreads();

    const int lane = tid & 63;
    const int wave = tid >> 6;
    const int lrow = lane & 15;         // A row within 16-tile / D col (c mod 16)
    const int lk   = (lane >> 4) * 8;   // k base for A/B fragments
    const int arow = wave * 16 + lrow;  // u row within block tile

    // bias values for this lane's columns
    const bool v2 = (lrow < 2);
    const float bo0 = b_out[lrow];
    const float bo1 = b_out[16 + lrow];
    const float bo2 = v2 ? b_out[32 + lrow] : 0.f;

    f32x4 acc[TT][3];
#pragma unroll
    for (int tt = 0; tt < TT; ++tt)
#pragma unroll
        for (int nt = 0; nt < 3; ++nt)
            acc[tt][nt] = (f32x4){0.f, 0.f, 0.f, 0.f};

    for (int kk = 0; kk < 10; ++kk) {
        const int k = lk + kk * 32;
        bf16x8 pv = *(const bf16x8*)&p_lds[arow * LDP + k];
        bf16x8 w0 = *(const bf16x8*)&w_lds[(0 * 16 + lrow) * LDP + k];
        bf16x8 w1 = *(const bf16x8*)&w_lds[(1 * 16 + lrow) * LDP + k];
        bf16x8 w2 = *(const bf16x8*)&w_lds[(2 * 16 + lrow) * LDP + k];
#pragma unroll
        for (int tt = 0; tt < TT; ++tt) {
            bf16x8 ev = *(const bf16x8*)&e_lds[tt * LDP + k];
            bf16x8 h;
#pragma unroll
            for (int x = 0; x < 8; ++x) {
                float f = (float)pv[x] + (float)ev[x];
                h[x] = (__bf16)fmaxf(f, 0.f);
            }
            acc[tt][0] = __builtin_amdgcn_mfma_f32_16x16x32_bf16(h, w0, acc[tt][0], 0, 0, 0);
            acc[tt][1] = __builtin_amdgcn_mfma_f32_16x16x32_bf16(h, w1, acc[tt][1], 0, 0, 0);
            acc[tt][2] = __builtin_amdgcn_mfma_f32_16x16x32_bf16(h, w2, acc[tt][2], 0, 0, 0);
        }
    }

    // ---- epilogue: per-row log_softmax over 34 classes, register-only ----
    // D layout: col = lane&15 (+16*nt), row = (lane>>4)*4 + i
#pragma unroll
    for (int tt = 0; tt < TT; ++tt) {
        const size_t rowbase = ((size_t)b * T_ + (t0 + tt)) * U_ + u0 + wave * 16;
#pragma unroll
        for (int i = 0; i < 4; ++i) {
            const int rl = (lane >> 4) * 4 + i;
            float v0 = acc[tt][0][i] + bo0;
            float v1 = acc[tt][1][i] + bo1;
            float vv2 = v2 ? (acc[tt][2][i] + bo2) : -INFINITY;
            float m = fmaxf(fmaxf(v0, v1), vv2);
#pragma unroll
            for (int d = 1; d < 16; d <<= 1) m = fmaxf(m, __shfl_xor(m, d, 64));
            float s = __expf(v0 - m) + __expf(v1 - m) + (v2 ? __expf(vv2 - m) : 0.f);
#pragma unroll
            for (int d = 1; d < 16; d <<= 1) s += __shfl_xor(s, d, 64);
            const float lse = m + __logf(s);
            float* po = out + (rowbase + rl) * C_;
            po[lrow]      = v0 - lse;
            po[16 + lrow] = v1 - lse;
            if (v2) po[32 + lrow] = vv2 - lse;
        }
    }
}

extern "C" void kernel_launch(void* const* d_in, const int* in_sizes, int n_in,
                              void* d_out, int out_size, void* d_ws, size_t ws_size,
                              hipStream_t stream) {
    const float* enc    = (const float*)d_in[0];
    const float* dec    = (const float*)d_in[1];
    const float* W_enc  = (const float*)d_in[2];
    const float* b_enc  = (const float*)d_in[3];
    const float* W_pred = (const float*)d_in[4];
    const float* b_pred = (const float*)d_in[5];
    const float* W_out  = (const float*)d_in[6];
    const float* b_out  = (const float*)d_in[7];
    float* out = (float*)d_out;

    ushort* e_bf = (ushort*)d_ws;                       // (B,T,JH) bf16
    ushort* p_bf = e_bf + (size_t)B_ * T_ * JH_;        // (B,U,JH) bf16

    // e = enc^T @ W_enc^T + b_enc  -> bf16
    proj_kernel<<<dim3(B_, JH_ / 16, T_ / 128), 128, 0, stream>>>(enc, W_enc, b_enc, e_bf, EH_, T_);
    // p = dec^T @ W_pred^T + b_pred -> bf16
    proj_kernel<<<dim3(B_, JH_ / 16, U_ / 128), 128, 0, stream>>>(dec, W_pred, b_pred, p_bf, PH_, U_);
    // fused joint + log_softmax
    joint_kernel<<<dim3(T_ / TT, 2, B_), 256, 0, stream>>>(e_bf, p_bf, W_out, b_out, out);
}

// Round 2
// 182.009 us; speedup vs baseline: 4.1198x; 4.1198x over previous
//
#include <hip/hip_runtime.h>

#define B_ 8
#define EH_ 768
#define T_ 512
#define PH_ 320
#define U_ 128
#define JH_ 320
#define C_ 34
#define TT 4          // t-rows per joint block
#define LDP 328       // joint LDS row stride (ushorts)
#define LDK 88        // proj LDS row stride (ushorts): 176B, 16B-aligned, 2-way-only bank aliasing

typedef __bf16 bf16x8 __attribute__((ext_vector_type(8)));
typedef float f32x4 __attribute__((ext_vector_type(4)));

static __device__ __forceinline__ ushort f2bf(float f) {
    union { float f; unsigned u; } cv; cv.f = f;
    unsigned u = cv.u;
    unsigned r = (u + 0x7fffu + ((u >> 16) & 1u)) >> 16;   // RNE
    return (ushort)r;
}

// ---------------------------------------------------------------------------
// MFMA projection: dst[b,n,j] = bias[j] + sum_h src[b,h,n] * W[j,h]  (bf16 out)
// A = src^T tile (32 n-rows x 64 k), B = W tile (80 j-rows x 64 k), both bf16 in LDS.
// grid: (N/32, JH/80, B), block 256 (4 waves).
//   wave: nsub = w&1 (16 rows), j-set = (w>>1) ? {3,4} : {0,1,2}
// ---------------------------------------------------------------------------
__global__ __launch_bounds__(256) void proj_mfma_kernel(
    const float* __restrict__ src, const float* __restrict__ W,
    const float* __restrict__ bias, ushort* __restrict__ dst,
    int H, int N)
{
    __shared__ alignas(16) ushort a_lds[32 * LDK];
    __shared__ alignas(16) ushort w_lds[80 * LDK];

    const int tid = threadIdx.x;
    const int n0  = blockIdx.x * 32;
    const int jg  = blockIdx.y;            // j-group of 80
    const int b   = blockIdx.z;

    const float* srcB = src + (size_t)b * H * N;
    const float* Wg   = W + (size_t)jg * 80 * H;

    const int nchunks = H / 64;

    // per-thread staging coords
    const int a_kk[2]  = { (tid + 0) >> 3, (tid + 256) >> 3 };
    const int a_nn4    = (tid & 7) * 4;
    const int w_jj[5]  = { tid >> 4, (tid + 256) >> 4, (tid + 512) >> 4, (tid + 768) >> 4, (tid + 1024) >> 4 };
    const int w_kk4    = (tid & 15) * 4;

    float4 aR[2], wR[5];

    // prefetch chunk 0
#pragma unroll
    for (int p = 0; p < 2; ++p)
        aR[p] = *(const float4*)&srcB[(size_t)a_kk[p] * N + n0 + a_nn4];
#pragma unroll
    for (int q = 0; q < 5; ++q)
        wR[q] = *(const float4*)&Wg[(size_t)w_jj[q] * H + w_kk4];

    const int lane = tid & 63;
    const int wave = tid >> 6;
    const int lrow = lane & 15;
    const int lk   = (lane >> 4) * 8;
    const int arow = (wave & 1) * 16 + lrow;
    const int jt0  = (wave >> 1) * 3;              // 0 or 3
    const int njt  = (wave >> 1) ? 2 : 3;

    f32x4 acc[3];
#pragma unroll
    for (int jt = 0; jt < 3; ++jt) acc[jt] = (f32x4){0.f, 0.f, 0.f, 0.f};

    for (int c = 0; c < nchunks; ++c) {
        // regs -> LDS (bf16)
#pragma unroll
        for (int p = 0; p < 2; ++p) {
#pragma unroll
            for (int x = 0; x < 4; ++x)
                a_lds[(a_nn4 + x) * LDK + a_kk[p]] = f2bf(aR[p][x]);
        }
#pragma unroll
        for (int q = 0; q < 5; ++q) {
            ushort4 wb;
            wb.x = f2bf(wR[q].x); wb.y = f2bf(wR[q].y);
            wb.z = f2bf(wR[q].z); wb.w = f2bf(wR[q].w);
            *(ushort4*)&w_lds[w_jj[q] * LDK + w_kk4] = wb;
        }
        __syncthreads();

        // prefetch next chunk (loads fly over the MFMA work below)
        if (c + 1 < nchunks) {
            const int k0 = (c + 1) * 64;
#pragma unroll
            for (int p = 0; p < 2; ++p)
                aR[p] = *(const float4*)&srcB[(size_t)(k0 + a_kk[p]) * N + n0 + a_nn4];
#pragma unroll
            for (int q = 0; q < 5; ++q)
                wR[q] = *(const float4*)&Wg[(size_t)w_jj[q] * H + k0 + w_kk4];
        }

        // compute: 2 k-steps of 32
#pragma unroll
        for (int ks = 0; ks < 2; ++ks) {
            const int k = ks * 32 + lk;
            bf16x8 af = *(const bf16x8*)&a_lds[arow * LDK + k];
#pragma unroll
            for (int jt = 0; jt < 3; ++jt) {
                if (jt < njt) {
                    bf16x8 wf = *(const bf16x8*)&w_lds[((jt0 + jt) * 16 + lrow) * LDK + k];
                    acc[jt] = __builtin_amdgcn_mfma_f32_16x16x32_bf16(af, wf, acc[jt], 0, 0, 0);
                }
            }
        }
        __syncthreads();
    }

    // epilogue: D row = n (quad*4+i), col = j (lane&15); add bias, write bf16
    const int quad = lane >> 4;
#pragma unroll
    for (int jt = 0; jt < 3; ++jt) {
        if (jt < njt) {
            const int j = jg * 80 + (jt0 + jt) * 16 + lrow;
            const float bv = bias[j];
#pragma unroll
            for (int i = 0; i < 4; ++i) {
                const int n = n0 + (wave & 1) * 16 + quad * 4 + i;
                dst[((size_t)b * N + n) * JH_ + j] = f2bf(acc[jt][i] + bv);
            }
        }
    }
}

// ---------------------------------------------------------------------------
// Fused joint: logits = relu(e[t]+p[u]) @ W_out^T + b_out, then log_softmax (C=34)
// grid: (T/TT, 2, B), block 256 (4 waves). Tile: TT t x 64 u x 48 c.
// ---------------------------------------------------------------------------
__global__ __launch_bounds__(256) void joint_kernel(
    const ushort* __restrict__ e_bf, const ushort* __restrict__ p_bf,
    const float* __restrict__ W_out, const float* __restrict__ b_out,
    float* __restrict__ out)
{
    __shared__ alignas(16) ushort p_lds[64 * LDP];
    __shared__ alignas(16) ushort w_lds[48 * LDP];
    __shared__ alignas(16) ushort e_lds[TT * LDP];

    const int tid = threadIdx.x;
    const int t0  = blockIdx.x * TT;
    const int u0  = blockIdx.y * 64;
    const int b   = blockIdx.z;

    {
        const uint4* src = (const uint4*)(p_bf + ((size_t)b * U_ + u0) * JH_);
        for (int i = tid; i < 64 * 40; i += 256) {
            int r = i / 40, k8 = i % 40;
            uint4 v = src[i];
            *(uint4*)&p_lds[r * LDP + k8 * 8] = v;
        }
    }
    {
        for (int i = tid; i < 48 * 80; i += 256) {
            int c = i / 80, k4 = i % 80;
            float4 w = (c < C_) ? ((const float4*)W_out)[c * 80 + k4] : make_float4(0.f, 0.f, 0.f, 0.f);
            ushort4 wb;
            wb.x = f2bf(w.x); wb.y = f2bf(w.y); wb.z = f2bf(w.z); wb.w = f2bf(w.w);
            *(ushort4*)&w_lds[c * LDP + k4 * 4] = wb;
        }
    }
    {
        const uint4* src = (const uint4*)(e_bf + ((size_t)b * T_ + t0) * JH_);
        for (int i = tid; i < TT * 40; i += 256) {
            int r = i / 40, k8 = i % 40;
            *(uint4*)&e_lds[r * LDP + k8 * 8] = src[i];
        }
    }
    __syncthreads();

    const int lane = tid & 63;
    const int wave = tid >> 6;
    const int lrow = lane & 15;
    const int lk   = (lane >> 4) * 8;
    const int arow = wave * 16 + lrow;

    const bool v2 = (lrow < 2);
    const float bo0 = b_out[lrow];
    const float bo1 = b_out[16 + lrow];
    const float bo2 = v2 ? b_out[32 + lrow] : 0.f;

    f32x4 acc[TT][3];
#pragma unroll
    for (int tt = 0; tt < TT; ++tt)
#pragma unroll
        for (int nt = 0; nt < 3; ++nt)
            acc[tt][nt] = (f32x4){0.f, 0.f, 0.f, 0.f};

    for (int kk = 0; kk < 10; ++kk) {
        const int k = lk + kk * 32;
        bf16x8 pv = *(const bf16x8*)&p_lds[arow * LDP + k];
        bf16x8 w0 = *(const bf16x8*)&w_lds[(0 * 16 + lrow) * LDP + k];
        bf16x8 w1 = *(const bf16x8*)&w_lds[(1 * 16 + lrow) * LDP + k];
        bf16x8 w2 = *(const bf16x8*)&w_lds[(2 * 16 + lrow) * LDP + k];
#pragma unroll
        for (int tt = 0; tt < TT; ++tt) {
            bf16x8 ev = *(const bf16x8*)&e_lds[tt * LDP + k];
            bf16x8 h;
#pragma unroll
            for (int x = 0; x < 8; ++x) {
                float f = (float)pv[x] + (float)ev[x];
                h[x] = (__bf16)fmaxf(f, 0.f);
            }
            acc[tt][0] = __builtin_amdgcn_mfma_f32_16x16x32_bf16(h, w0, acc[tt][0], 0, 0, 0);
            acc[tt][1] = __builtin_amdgcn_mfma_f32_16x16x32_bf16(h, w1, acc[tt][1], 0, 0, 0);
            acc[tt][2] = __builtin_amdgcn_mfma_f32_16x16x32_bf16(h, w2, acc[tt][2], 0, 0, 0);
        }
    }

#pragma unroll
    for (int tt = 0; tt < TT; ++tt) {
        const size_t rowbase = ((size_t)b * T_ + (t0 + tt)) * U_ + u0 + wave * 16;
#pragma unroll
        for (int i = 0; i < 4; ++i) {
            const int rl = (lane >> 4) * 4 + i;
            float v0 = acc[tt][0][i] + bo0;
            float v1 = acc[tt][1][i] + bo1;
            float vv2 = v2 ? (acc[tt][2][i] + bo2) : -INFINITY;
            float m = fmaxf(fmaxf(v0, v1), vv2);
#pragma unroll
            for (int d = 1; d < 16; d <<= 1) m = fmaxf(m, __shfl_xor(m, d, 64));
            float s = __expf(v0 - m) + __expf(v1 - m) + (v2 ? __expf(vv2 - m) : 0.f);
#pragma unroll
            for (int d = 1; d < 16; d <<= 1) s += __shfl_xor(s, d, 64);
            const float lse = m + __logf(s);
            float* po = out + (rowbase + rl) * C_;
            po[lrow]      = v0 - lse;
            po[16 + lrow] = v1 - lse;
            if (v2) po[32 + lrow] = vv2 - lse;
        }
    }
}

extern "C" void kernel_launch(void* const* d_in, const int* in_sizes, int n_in,
                              void* d_out, int out_size, void* d_ws, size_t ws_size,
                              hipStream_t stream) {
    const float* enc    = (const float*)d_in[0];
    const float* dec    = (const float*)d_in[1];
    const float* W_enc  = (const float*)d_in[2];
    const float* b_enc  = (const float*)d_in[3];
    const float* W_pred = (const float*)d_in[4];
    const float* b_pred = (const float*)d_in[5];
    const float* W_out  = (const float*)d_in[6];
    const float* b_out  = (const float*)d_in[7];
    float* out = (float*)d_out;

    ushort* e_bf = (ushort*)d_ws;                       // (B,T,JH) bf16
    ushort* p_bf = e_bf + (size_t)B_ * T_ * JH_;        // (B,U,JH) bf16

    proj_mfma_kernel<<<dim3(T_ / 32, JH_ / 80, B_), 256, 0, stream>>>(enc, W_enc, b_enc, e_bf, EH_, T_);
    proj_mfma_kernel<<<dim3(U_ / 32, JH_ / 80, B_), 256, 0, stream>>>(dec, W_pred, b_pred, p_bf, PH_, U_);
    joint_kernel<<<dim3(T_ / TT, 2, B_), 256, 0, stream>>>(e_bf, p_bf, W_out, b_out, out);
}

// Round 4
// 166.549 us; speedup vs baseline: 4.5023x; 1.0928x over previous
//
#include <hip/hip_runtime.h>

#define B_ 8
#define EH_ 768
#define T_ 512
#define PH_ 320
#define U_ 128
#define JH_ 320
#define C_ 34
#define TTJ 8         // t-rows per joint block
#define LDP 328       // joint LDS row stride in halfs (320 + 8 pad, 16B-aligned)

typedef _Float16 f16x8 __attribute__((ext_vector_type(8)));
typedef _Float16 f16x4 __attribute__((ext_vector_type(4)));
typedef float f32x4 __attribute__((ext_vector_type(4)));

// ---- DPP 16-lane butterfly reductions (VALU pipe, not LDS) ----
template <int CTRL>
static __device__ __forceinline__ float dpp_mov(float x) {
    int xi = __builtin_bit_cast(int, x);
    return __builtin_bit_cast(float, __builtin_amdgcn_update_dpp(xi, xi, CTRL, 0xf, 0xf, true));
}
static __device__ __forceinline__ float red16_max(float x) {
    x = fmaxf(x, dpp_mov<0xB1>(x));    // quad_perm xor1
    x = fmaxf(x, dpp_mov<0x4E>(x));    // quad_perm xor2
    x = fmaxf(x, dpp_mov<0x141>(x));   // row_half_mirror (xor4)
    x = fmaxf(x, dpp_mov<0x140>(x));   // row_mirror (xor8)
    return x;
}
static __device__ __forceinline__ float red16_sum(float x) {
    x += dpp_mov<0xB1>(x);
    x += dpp_mov<0x4E>(x);
    x += dpp_mov<0x141>(x);
    x += dpp_mov<0x140>(x);
    return x;
}

// relu(a+b) on 8 packed halves: v_pk_add_f16 + v_pk_max_f16
static __device__ __forceinline__ f16x8 relu_sum8(f16x8 a, f16x8 b) {
    f16x8 s = a + b;
    f16x8 z = (f16x8)(_Float16)0.f;
    return __builtin_elementwise_max(s, z);
}

// ---------------------------------------------------------------------------
// Pre-pass 1: transpose + convert  src (b,H,N) f32  ->  dst (b,N,H) f16
// grid (N/32, H/32, B), block 256
// ---------------------------------------------------------------------------
__global__ __launch_bounds__(256) void transpose_cvt_kernel(
    const float* __restrict__ src, _Float16* __restrict__ dst, int H, int N)
{
    __shared__ _Float16 tile[32][36];
    const int tid = threadIdx.x;
    const int tx = tid & 7, ty = tid >> 3;
    const int n0 = blockIdx.x * 32, h0 = blockIdx.y * 32, b = blockIdx.z;

    float4 v = *(const float4*)&src[((size_t)b * H + h0 + ty) * N + n0 + tx * 4];
    f16x4 t;
    t[0] = (_Float16)v.x; t[1] = (_Float16)v.y; t[2] = (_Float16)v.z; t[3] = (_Float16)v.w;
    *(f16x4*)&tile[ty][tx * 4] = t;
    __syncthreads();

    f16x4 o;
    o[0] = tile[tx * 4 + 0][ty];
    o[1] = tile[tx * 4 + 1][ty];
    o[2] = tile[tx * 4 + 2][ty];
    o[3] = tile[tx * 4 + 3][ty];
    *(f16x4*)&dst[((size_t)b * N + n0 + ty) * H + h0 + tx * 4] = o;
}

// ---------------------------------------------------------------------------
// Pre-pass 2: convert W_enc, W_pred to f16; W_out to padded 48x320 f16 (zeros c>=34)
// ---------------------------------------------------------------------------
__global__ void weights_cvt_kernel(
    const float* __restrict__ Wenc, const float* __restrict__ Wpred,
    const float* __restrict__ Wout,
    _Float16* __restrict__ wenc, _Float16* __restrict__ wpred, _Float16* __restrict__ wout)
{
    const int t1 = JH_ * EH_, t2 = JH_ * PH_, t3 = 48 * JH_;
    int i = blockIdx.x * 256 + threadIdx.x;
    if (i < t1) {
        wenc[i] = (_Float16)Wenc[i];
    } else if (i < t1 + t2) {
        wpred[i - t1] = (_Float16)Wpred[i - t1];
    } else if (i < t1 + t2 + t3) {
        int k = i - t1 - t2;
        int c = k / JH_;
        wout[k] = (c < C_) ? (_Float16)Wout[k] : (_Float16)0.f;
    }
}

// ---------------------------------------------------------------------------
// Projection, barrier-free: dst[b,n,j] = bias[j] + sum_h src_t[b,n,h]*Wf[j,h]
// Each wave: 32n x 32j tile; all fragments are single b128 global loads (L2-hot).
// grid ((N/32)*(JH/32)*B/4), block 256 (4 independent waves)
// ---------------------------------------------------------------------------
__global__ __launch_bounds__(256) void proj_direct_kernel(
    const _Float16* __restrict__ src_t, const _Float16* __restrict__ Wf,
    const float* __restrict__ bias, _Float16* __restrict__ dst, int H, int N)
{
    const int tid = threadIdx.x;
    const int wave = tid >> 6, lane = tid & 63;
    const int lrow = lane & 15, quad = lane >> 4;
    const int ntn = N / 32;

    int gid = blockIdx.x * 4 + wave;
    const int nt_ = gid % ntn; gid /= ntn;
    const int jt_ = gid % (JH_ / 32);
    const int b   = gid / (JH_ / 32);
    const int n0 = nt_ * 32, j0 = jt_ * 32;

    const _Float16* a0p = src_t + ((size_t)b * N + n0 + lrow) * H + quad * 8;
    const _Float16* a1p = a0p + (size_t)16 * H;
    const _Float16* w0p = Wf + (size_t)(j0 + lrow) * H + quad * 8;
    const _Float16* w1p = w0p + (size_t)16 * H;

    f32x4 acc00 = {0.f,0.f,0.f,0.f}, acc01 = {0.f,0.f,0.f,0.f};
    f32x4 acc10 = {0.f,0.f,0.f,0.f}, acc11 = {0.f,0.f,0.f,0.f};

#pragma unroll 2
    for (int k = 0; k < H; k += 32) {
        f16x8 a0 = *(const f16x8*)(a0p + k);
        f16x8 a1 = *(const f16x8*)(a1p + k);
        f16x8 w0 = *(const f16x8*)(w0p + k);
        f16x8 w1 = *(const f16x8*)(w1p + k);
        acc00 = __builtin_amdgcn_mfma_f32_16x16x32_f16(a0, w0, acc00, 0, 0, 0);
        acc01 = __builtin_amdgcn_mfma_f32_16x16x32_f16(a0, w1, acc01, 0, 0, 0);
        acc10 = __builtin_amdgcn_mfma_f32_16x16x32_f16(a1, w0, acc10, 0, 0, 0);
        acc11 = __builtin_amdgcn_mfma_f32_16x16x32_f16(a1, w1, acc11, 0, 0, 0);
    }

    const float bj0 = bias[j0 + lrow];
    const float bj1 = bias[j0 + 16 + lrow];
    // D: row(n) = quad*4+i, col(j) = lane&15
#pragma unroll
    for (int nt = 0; nt < 2; ++nt) {
        const f32x4 ac0 = nt ? acc10 : acc00;
        const f32x4 ac1 = nt ? acc11 : acc01;
#pragma unroll
        for (int i = 0; i < 4; ++i) {
            const int n = n0 + nt * 16 + quad * 4 + i;
            _Float16* d = dst + ((size_t)b * N + n) * JH_ + j0;
            d[lrow]      = (_Float16)(ac0[i] + bj0);
            d[16 + lrow] = (_Float16)(ac1[i] + bj1);
        }
    }
}

// ---------------------------------------------------------------------------
// Fused joint: logits = relu(e[t]+p[u]) @ W_out^T + b_out, log_softmax over C=34
// grid (T/TTJ, 2, B), block 256 (4 waves). Tile: TTJ t x 64 u x 48 c.
// ---------------------------------------------------------------------------
__global__ __launch_bounds__(256) void joint_kernel(
    const _Float16* __restrict__ e_f, const _Float16* __restrict__ p_f,
    const _Float16* __restrict__ wout_f, const float* __restrict__ b_out,
    float* __restrict__ out)
{
    __shared__ alignas(16) _Float16 p_lds[64 * LDP];
    __shared__ alignas(16) _Float16 w_lds[48 * LDP];
    __shared__ alignas(16) _Float16 e_lds[TTJ * LDP];

    const int tid = threadIdx.x;
    const int t0  = blockIdx.x * TTJ;
    const int u0  = blockIdx.y * 64;
    const int b   = blockIdx.z;

    {
        const uint4* sp = (const uint4*)(p_f + ((size_t)b * U_ + u0) * JH_);
        for (int i = tid; i < 64 * 40; i += 256) {
            int r = i / 40, k8 = i % 40;
            *(uint4*)&p_lds[r * LDP + k8 * 8] = sp[i];
        }
        const uint4* sw = (const uint4*)wout_f;
        for (int i = tid; i < 48 * 40; i += 256) {
            int r = i / 40, k8 = i % 40;
            *(uint4*)&w_lds[r * LDP + k8 * 8] = sw[i];
        }
        const uint4* se = (const uint4*)(e_f + ((size_t)b * T_ + t0) * JH_);
        for (int i = tid; i < TTJ * 40; i += 256) {
            int r = i / 40, k8 = i % 40;
            *(uint4*)&e_lds[r * LDP + k8 * 8] = se[i];
        }
    }
    __syncthreads();

    const int lane = tid & 63;
    const int wave = tid >> 6;
    const int lrow = lane & 15;
    const int quad = lane >> 4;
    const int lk   = quad * 8;
    const int arow = wave * 16 + lrow;   // u-row within 64-tile

    const bool v2 = (lrow < 2);
    const float bo0 = b_out[lrow];
    const float bo1 = b_out[16 + lrow];
    const float bo2 = v2 ? b_out[32 + lrow] : 0.f;

    f32x4 acc[TTJ][3];
#pragma unroll
    for (int tt = 0; tt < TTJ; ++tt)
#pragma unroll
        for (int nt = 0; nt < 3; ++nt)
            acc[tt][nt] = (f32x4){0.f, 0.f, 0.f, 0.f};

    for (int kk = 0; kk < 10; ++kk) {
        const int k = lk + kk * 32;
        f16x8 pv = *(const f16x8*)&p_lds[arow * LDP + k];
        f16x8 w0 = *(const f16x8*)&w_lds[(0 * 16 + lrow) * LDP + k];
        f16x8 w1 = *(const f16x8*)&w_lds[(1 * 16 + lrow) * LDP + k];
        f16x8 w2 = *(const f16x8*)&w_lds[(2 * 16 + lrow) * LDP + k];
#pragma unroll
        for (int tt = 0; tt < TTJ; ++tt) {
            f16x8 ev = *(const f16x8*)&e_lds[tt * LDP + k];   // quad-broadcast
            f16x8 h = relu_sum8(pv, ev);
            acc[tt][0] = __builtin_amdgcn_mfma_f32_16x16x32_f16(h, w0, acc[tt][0], 0, 0, 0);
            acc[tt][1] = __builtin_amdgcn_mfma_f32_16x16x32_f16(h, w1, acc[tt][1], 0, 0, 0);
            acc[tt][2] = __builtin_amdgcn_mfma_f32_16x16x32_f16(h, w2, acc[tt][2], 0, 0, 0);
        }
    }

    // epilogue: per (t,u)-row log_softmax; row = quad*4+i (u), col = lane&15 (c mod 16)
#pragma unroll
    for (int tt = 0; tt < TTJ; ++tt) {
        const size_t rowbase = ((size_t)b * T_ + (t0 + tt)) * U_ + u0 + wave * 16;
#pragma unroll
        for (int i = 0; i < 4; ++i) {
            const int rl = quad * 4 + i;
            float v0  = acc[tt][0][i] + bo0;
            float v1  = acc[tt][1][i] + bo1;
            float vv2 = v2 ? (acc[tt][2][i] + bo2) : -INFINITY;
            float m = red16_max(fmaxf(fmaxf(v0, v1), vv2));
            float s = __expf(v0 - m) + __expf(v1 - m) + (v2 ? __expf(vv2 - m) : 0.f);
            s = red16_sum(s);
            const float lse = m + __logf(s);
            float* po = out + (rowbase + rl) * C_;
            po[lrow]      = v0 - lse;
            po[16 + lrow] = v1 - lse;
            if (v2) po[32 + lrow] = vv2 - lse;
        }
    }
}

extern "C" void kernel_launch(void* const* d_in, const int* in_sizes, int n_in,
                              void* d_out, int out_size, void* d_ws, size_t ws_size,
                              hipStream_t stream) {
    const float* enc    = (const float*)d_in[0];
    const float* dec    = (const float*)d_in[1];
    const float* W_enc  = (const float*)d_in[2];
    const float* b_enc  = (const float*)d_in[3];
    const float* W_pred = (const float*)d_in[4];
    const float* b_pred = (const float*)d_in[5];
    const float* W_out  = (const float*)d_in[6];
    const float* b_out  = (const float*)d_in[7];
    float* out = (float*)d_out;

    // workspace layout (halfs): ~10.9 MB total
    _Float16* enc_t  = (_Float16*)d_ws;                         // (B,T,EH)
    _Float16* dec_t  = enc_t  + (size_t)B_ * T_ * EH_;          // (B,U,PH)
    _Float16* wenc_f = dec_t  + (size_t)B_ * U_ * PH_;          // (JH,EH)
    _Float16* wpred_f= wenc_f + (size_t)JH_ * EH_;              // (JH,PH)
    _Float16* wout_f = wpred_f+ (size_t)JH_ * PH_;              // (48,JH) padded
    _Float16* e_f    = wout_f + (size_t)48 * JH_;               // (B,T,JH)
    _Float16* p_f    = e_f    + (size_t)B_ * T_ * JH_;          // (B,U,JH)

    transpose_cvt_kernel<<<dim3(T_ / 32, EH_ / 32, B_), 256, 0, stream>>>(enc, enc_t, EH_, T_);
    transpose_cvt_kernel<<<dim3(U_ / 32, PH_ / 32, B_), 256, 0, stream>>>(dec, dec_t, PH_, U_);
    weights_cvt_kernel<<<dim3((JH_ * EH_ + JH_ * PH_ + 48 * JH_ + 255) / 256), 256, 0, stream>>>(
        W_enc, W_pred, W_out, wenc_f, wpred_f, wout_f);

    proj_direct_kernel<<<dim3((T_ / 32) * (JH_ / 32) * B_ / 4), 256, 0, stream>>>(
        enc_t, wenc_f, b_enc, e_f, EH_, T_);
    proj_direct_kernel<<<dim3((U_ / 32) * (JH_ / 32) * B_ / 4), 256, 0, stream>>>(
        dec_t, wpred_f, b_pred, p_f, PH_, U_);

    joint_kernel<<<dim3(T_ / TTJ, 2, B_), 256, 0, stream>>>(e_f, p_f, wout_f, b_out, out);
}

// Round 5
// 153.026 us; speedup vs baseline: 4.9001x; 1.0884x over previous
//
#include <hip/hip_runtime.h>

#define B_ 8
#define EH_ 768
#define T_ 512
#define PH_ 320
#define U_ 128
#define JH_ 320
#define C_ 34
#define LDP 328       // LDS row stride in halfs (656 B = 4-bank offset -> free 2-way)

typedef _Float16 f16x8 __attribute__((ext_vector_type(8)));
typedef _Float16 f16x4 __attribute__((ext_vector_type(4)));
typedef float f32x4 __attribute__((ext_vector_type(4)));

// relu(a+b) on 8 packed halves: v_pk_add_f16 + v_pk_max_f16
static __device__ __forceinline__ f16x8 relu_sum8(f16x8 a, f16x8 b) {
    f16x8 s = a + b;
    f16x8 z = (f16x8)(_Float16)0.f;
    return __builtin_elementwise_max(s, z);
}

// ---------------------------------------------------------------------------
// Fused prep: transpose+cvt enc and dec (b,H,N)f32 -> (b,N,H)f16, cvt weights.
// 1-D grid, branch on block range.
//   enc blocks: (T/32)*(EH/32)*B = 16*24*8 = 3072
//   dec blocks: (U/32)*(PH/32)*B = 4*10*8  = 320
//   weights:    ceil((320*768 + 320*320 + 34*320)/256) = 1403
// ---------------------------------------------------------------------------
__global__ __launch_bounds__(256) void prep_kernel(
    const float* __restrict__ enc, const float* __restrict__ dec,
    const float* __restrict__ Wenc, const float* __restrict__ Wpred,
    const float* __restrict__ Wout,
    _Float16* __restrict__ enc_t, _Float16* __restrict__ dec_t,
    _Float16* __restrict__ wenc, _Float16* __restrict__ wpred,
    _Float16* __restrict__ wout)
{
    __shared__ _Float16 tile[32][36];
    const int NE = 16 * 24 * B_;
    const int ND = 4 * 10 * B_;
    const int tid = threadIdx.x;
    int bid = blockIdx.x;

    if (bid < NE + ND) {
        const float* src; _Float16* dst; int H, N, n0, h0, b;
        if (bid < NE) {
            src = enc; dst = enc_t; H = EH_; N = T_;
            n0 = (bid % 16) * 32; h0 = ((bid / 16) % 24) * 32; b = bid / (16 * 24);
        } else {
            int i = bid - NE;
            src = dec; dst = dec_t; H = PH_; N = U_;
            n0 = (i % 4) * 32; h0 = ((i / 4) % 10) * 32; b = i / 40;
        }
        const int tx = tid & 7, ty = tid >> 3;
        float4 v = *(const float4*)&src[((size_t)b * H + h0 + ty) * N + n0 + tx * 4];
        f16x4 t;
        t[0] = (_Float16)v.x; t[1] = (_Float16)v.y; t[2] = (_Float16)v.z; t[3] = (_Float16)v.w;
        *(f16x4*)&tile[ty][tx * 4] = t;
        __syncthreads();
        f16x4 o;
        o[0] = tile[tx * 4 + 0][ty];
        o[1] = tile[tx * 4 + 1][ty];
        o[2] = tile[tx * 4 + 2][ty];
        o[3] = tile[tx * 4 + 3][ty];
        *(f16x4*)&dst[((size_t)b * N + n0 + ty) * H + h0 + tx * 4] = o;
    } else {
        const int t1 = JH_ * EH_, t2 = JH_ * PH_, t3 = C_ * JH_;
        int i = (bid - NE - ND) * 256 + tid;
        if (i < t1)                wenc[i] = (_Float16)Wenc[i];
        else if (i < t1 + t2)      wpred[i - t1] = (_Float16)Wpred[i - t1];
        else if (i < t1 + t2 + t3) wout[i - t1 - t2] = (_Float16)Wout[i - t1 - t2];
    }
}

// ---------------------------------------------------------------------------
// Fused projections (e and p): dst[b,n,j] = bias[j] + sum_h src_t[b,n,h]*W[j,h]
// One wave = 16n x 16j tile, pure-register MFMA, no barriers.
//   e waves: (T/16)*(JH/16)*B = 5120 ; p waves: (U/16)*(JH/16)*B = 1280
// grid 1600 x 256 (4 waves/block)
// ---------------------------------------------------------------------------
__global__ __launch_bounds__(256) void proj_kernel(
    const _Float16* __restrict__ enc_t, const _Float16* __restrict__ dec_t,
    const _Float16* __restrict__ wenc, const _Float16* __restrict__ wpred,
    const float* __restrict__ b_enc, const float* __restrict__ b_pred,
    _Float16* __restrict__ e_f, _Float16* __restrict__ p_f)
{
    const int tid = threadIdx.x;
    const int wave = tid >> 6, lane = tid & 63;
    const int lrow = lane & 15, quad = lane >> 4;

    int wid = blockIdx.x * 4 + wave;
    const int We = (T_ / 16) * (JH_ / 16) * B_;
    const _Float16 *src, *W; const float* bias; _Float16* dst; int H, N;
    if (wid < We) { src = enc_t; W = wenc;  bias = b_enc;  dst = e_f; H = EH_; N = T_; }
    else { wid -= We; src = dec_t; W = wpred; bias = b_pred; dst = p_f; H = PH_; N = U_; }

    const int ntn = N / 16;
    const int nt = wid % ntn; int r = wid / ntn;
    const int jt = r % (JH_ / 16); const int b = r / (JH_ / 16);
    const int n0 = nt * 16, j0 = jt * 16;

    const _Float16* ap = src + ((size_t)b * N + n0 + lrow) * H + quad * 8;
    const _Float16* wp = W + (size_t)(j0 + lrow) * H + quad * 8;

    f32x4 acc = {0.f, 0.f, 0.f, 0.f};
#pragma unroll 4
    for (int k = 0; k < H; k += 32) {
        f16x8 af = *(const f16x8*)(ap + k);
        f16x8 wf = *(const f16x8*)(wp + k);
        acc = __builtin_amdgcn_mfma_f32_16x16x32_f16(wf, af, acc, 0, 0, 0);
    }
    // D: row = j (quad*4+i), col = n (lane&15)
    const float4 bj = *(const float4*)&bias[j0 + quad * 4];
    f16x4 o;
    o[0] = (_Float16)(acc[0] + bj.x);
    o[1] = (_Float16)(acc[1] + bj.y);
    o[2] = (_Float16)(acc[2] + bj.z);
    o[3] = (_Float16)(acc[3] + bj.w);
    *(f16x4*)&dst[((size_t)b * N + n0 + lrow) * JH_ + j0 + quad * 4] = o;
}

// ---------------------------------------------------------------------------
// Fused joint: logits = relu(e[t]+p[u]) @ W_out^T + b_out, log_softmax (C=34)
// grid (T/8, U/32, B), block 256. Tile: 8t x 32u x 48c; wave = 4t x 16u.
// LDS: [W 34 rows | p 32 rows | e 8 rows], 74*LDP halfs = 48.5 KB -> 3 blocks/CU.
// W's third MFMA fragment (rows 34..47) reads into the p region: garbage is
// confined to D-rows c>=34 which are never stored (D row = A row = c).
// ---------------------------------------------------------------------------
__global__ __launch_bounds__(256) void joint_kernel(
    const _Float16* __restrict__ e_f, const _Float16* __restrict__ p_f,
    const _Float16* __restrict__ wout_f, const float* __restrict__ b_out,
    float* __restrict__ out)
{
    __shared__ alignas(16) _Float16 lds[(34 + 32 + 8) * LDP];

    const int tid = threadIdx.x;
    const int t0 = blockIdx.x * 8;
    const int u0 = blockIdx.y * 32;
    const int b  = blockIdx.z;

    {
        const uint4* sw = (const uint4*)wout_f;
        for (int i = tid; i < 34 * 40; i += 256) {
            int rr = i / 40, k8 = i % 40;
            *(uint4*)&lds[rr * LDP + k8 * 8] = sw[i];
        }
        const uint4* sp = (const uint4*)(p_f + ((size_t)b * U_ + u0) * JH_);
        for (int i = tid; i < 32 * 40; i += 256) {
            int rr = i / 40, k8 = i % 40;
            *(uint4*)&lds[(34 + rr) * LDP + k8 * 8] = sp[i];
        }
        const uint4* se = (const uint4*)(e_f + ((size_t)b * T_ + t0) * JH_);
        for (int i = tid; i < 8 * 40; i += 256) {
            int rr = i / 40, k8 = i % 40;
            *(uint4*)&lds[(66 + rr) * LDP + k8 * 8] = se[i];
        }
    }
    __syncthreads();

    const int lane = tid & 63, wave = tid >> 6;
    const int lrow = lane & 15, quad = lane >> 4;
    const int lk = quad * 8;
    const int urow  = 34 + (wave & 1) * 16 + lrow;   // p row in LDS
    const int tbase = 66 + (wave >> 1) * 4;          // first e row for this wave

    f32x4 acc[4][3];
#pragma unroll
    for (int tt = 0; tt < 4; ++tt)
#pragma unroll
        for (int c = 0; c < 3; ++c) acc[tt][c] = (f32x4){0.f, 0.f, 0.f, 0.f};

    for (int kk = 0; kk < 10; ++kk) {
        const int k = lk + kk * 32;
        f16x8 pv = *(const f16x8*)&lds[urow * LDP + k];
        f16x8 w0 = *(const f16x8*)&lds[(0  + lrow) * LDP + k];
        f16x8 w1 = *(const f16x8*)&lds[(16 + lrow) * LDP + k];
        f16x8 w2 = *(const f16x8*)&lds[(32 + lrow) * LDP + k];   // rows>=34: garbage, confined
#pragma unroll
        for (int tt = 0; tt < 4; ++tt) {
            f16x8 ev = *(const f16x8*)&lds[(tbase + tt) * LDP + k];
            f16x8 h = relu_sum8(pv, ev);
            acc[tt][0] = __builtin_amdgcn_mfma_f32_16x16x32_f16(w0, h, acc[tt][0], 0, 0, 0);
            acc[tt][1] = __builtin_amdgcn_mfma_f32_16x16x32_f16(w1, h, acc[tt][1], 0, 0, 0);
            acc[tt][2] = __builtin_amdgcn_mfma_f32_16x16x32_f16(w2, h, acc[tt][2], 0, 0, 0);
        }
    }

    // D: row = c = nt*16 + quad*4 + i, col = u = lane&15
    const float4 bq0 = *(const float4*)&b_out[quad * 4];
    const float4 bq1 = *(const float4*)&b_out[16 + quad * 4];
    const bool q0 = (quad == 0);
    float b2x = 0.f, b2y = 0.f;
    if (q0) { b2x = b_out[32]; b2y = b_out[33]; }

    const int u = u0 + (wave & 1) * 16 + lrow;
#pragma unroll
    for (int tt = 0; tt < 4; ++tt) {
        float v0[4], v1[4];
        v0[0] = acc[tt][0][0] + bq0.x; v0[1] = acc[tt][0][1] + bq0.y;
        v0[2] = acc[tt][0][2] + bq0.z; v0[3] = acc[tt][0][3] + bq0.w;
        v1[0] = acc[tt][1][0] + bq1.x; v1[1] = acc[tt][1][1] + bq1.y;
        v1[2] = acc[tt][1][2] + bq1.z; v1[3] = acc[tt][1][3] + bq1.w;
        float v2x = q0 ? (acc[tt][2][0] + b2x) : -INFINITY;
        float v2y = q0 ? (acc[tt][2][1] + b2y) : -INFINITY;

        float m = fmaxf(fmaxf(fmaxf(v0[0], v0[1]), fmaxf(v0[2], v0[3])),
                        fmaxf(fmaxf(v1[0], v1[1]), fmaxf(v1[2], v1[3])));
        m = fmaxf(m, fmaxf(v2x, v2y));
        m = fmaxf(m, __shfl_xor(m, 16));
        m = fmaxf(m, __shfl_xor(m, 32));

        float s = __expf(v0[0] - m) + __expf(v0[1] - m) + __expf(v0[2] - m) + __expf(v0[3] - m)
                + __expf(v1[0] - m) + __expf(v1[1] - m) + __expf(v1[2] - m) + __expf(v1[3] - m);
        if (q0) s += __expf(v2x - m) + __expf(v2y - m);
        s += __shfl_xor(s, 16);
        s += __shfl_xor(s, 32);
        const float lse = m + __logf(s);

        const int t = t0 + (wave >> 1) * 4 + tt;
        float* po = out + (((size_t)b * T_ + t) * U_ + u) * C_;
        *(float2*)&po[quad * 4]          = make_float2(v0[0] - lse, v0[1] - lse);
        *(float2*)&po[quad * 4 + 2]      = make_float2(v0[2] - lse, v0[3] - lse);
        *(float2*)&po[16 + quad * 4]     = make_float2(v1[0] - lse, v1[1] - lse);
        *(float2*)&po[16 + quad * 4 + 2] = make_float2(v1[2] - lse, v1[3] - lse);
        if (q0) *(float2*)&po[32]        = make_float2(v2x - lse, v2y - lse);
    }
}

extern "C" void kernel_launch(void* const* d_in, const int* in_sizes, int n_in,
                              void* d_out, int out_size, void* d_ws, size_t ws_size,
                              hipStream_t stream) {
    const float* enc    = (const float*)d_in[0];
    const float* dec    = (const float*)d_in[1];
    const float* W_enc  = (const float*)d_in[2];
    const float* b_enc  = (const float*)d_in[3];
    const float* W_pred = (const float*)d_in[4];
    const float* b_pred = (const float*)d_in[5];
    const float* W_out  = (const float*)d_in[6];
    const float* b_out  = (const float*)d_in[7];
    float* out = (float*)d_out;

    _Float16* enc_t  = (_Float16*)d_ws;                         // (B,T,EH)
    _Float16* dec_t  = enc_t  + (size_t)B_ * T_ * EH_;          // (B,U,PH)
    _Float16* wenc_f = dec_t  + (size_t)B_ * U_ * PH_;          // (JH,EH)
    _Float16* wpred_f= wenc_f + (size_t)JH_ * EH_;              // (JH,PH)
    _Float16* wout_f = wpred_f+ (size_t)JH_ * PH_;              // (34,JH)
    _Float16* e_f    = wout_f + (size_t)C_ * JH_;               // (B,T,JH)
    _Float16* p_f    = e_f    + (size_t)B_ * T_ * JH_;          // (B,U,JH)

    const int NE = 16 * 24 * B_, ND = 4 * 10 * B_;
    const int NW = (JH_ * EH_ + JH_ * PH_ + C_ * JH_ + 255) / 256;
    prep_kernel<<<dim3(NE + ND + NW), 256, 0, stream>>>(
        enc, dec, W_enc, W_pred, W_out, enc_t, dec_t, wenc_f, wpred_f, wout_f);

    const int We = (T_ / 16) * (JH_ / 16) * B_;
    const int Wp = (U_ / 16) * (JH_ / 16) * B_;
    proj_kernel<<<dim3((We + Wp) / 4), 256, 0, stream>>>(
        enc_t, dec_t, wenc_f, wpred_f, b_enc, b_pred, e_f, p_f);

    joint_kernel<<<dim3(T_ / 8, U_ / 32, B_), 256, 0, stream>>>(e_f, p_f, wout_f, b_out, out);
}